// Round 5
// baseline (531.341 us; speedup 1.0000x reference)
//
#include <hip/hip_runtime.h>
#include <hip/hip_bf16.h>

#define NUSERS 200000
#define NITEMS 100000
#define NNODES 300000
#define EDIM   64
#define NEDGES 2000000
#define SCAN_NB ((NNODES + 255) / 256)   // 1172 blocks
#define FILL_BLOCKS 2048
#define NPASS 4
#define PREP_HB 2048                     // hist blocks (grid-stride)
#define PREP_CB 2048                     // convert blocks (grid-stride)
#define SPMM_BLOCKS 2048                 // 8 blocks/CU persistent
#define SPMM_STRIDE (SPMM_BLOCKS * 4)    // one node per wave per sweep
#define CPAD 16                          // counter padding: 1 int per 64B line

typedef unsigned short u16;

__device__ __forceinline__ float bf2f(u16 h) {
    return __uint_as_float((unsigned)h << 16);
}
__device__ __forceinline__ u16 f2bf(float f) {
    union { __hip_bfloat16 b; u16 u; } c;
    c.b = __float2bfloat16(f);   // RNE
    return c.u;
}

// ---------------- fused histogram + bf16 convert (grid-stride) ----------------
// R4 post-mortem: 112us at VALUBusy 1.4% regardless of grid shape -> NOT
// dispatch-bound. Theory: 2M atomics onto 300K densely packed ints = ~107
// RMWs per 64B L2 line, serialized per line. Fix: pad counters to one per
// line (cnt[d*16]) -> ~6.7 atomics/line.
__global__ void k_prep(const int4* __restrict__ dst4, int* __restrict__ cnt,
                       const float4* __restrict__ uq, const float4* __restrict__ iq,
                       ushort4* __restrict__ xb4) {
    int b = blockIdx.x;
    if (b < PREP_HB) {
        for (int i = b * 256 + threadIdx.x; i < NEDGES / 4; i += PREP_HB * 256) {
            int4 d = dst4[i];
            atomicAdd(&cnt[(unsigned)d.x << 4], 1);
            atomicAdd(&cnt[(unsigned)d.y << 4], 1);
            atomicAdd(&cnt[(unsigned)d.z << 4], 1);
            atomicAdd(&cnt[(unsigned)d.w << 4], 1);
        }
    } else {
        for (int i = (b - PREP_HB) * 256 + threadIdx.x; i < NNODES * 16;
             i += PREP_CB * 256) {
            float4 v = (i < NUSERS * 16) ? uq[i] : iq[i - NUSERS * 16];
            ushort4 h;
            h.x = f2bf(v.x); h.y = f2bf(v.y); h.z = f2bf(v.z); h.w = f2bf(v.w);
            xb4[i] = h;
        }
    }
}

// ---------------- scan: strided hist in -> dense off out ----------------

__global__ void k_scan1(const int* __restrict__ cntp, int* __restrict__ off,
                        int* __restrict__ bsum) {
    __shared__ int s[256];
    int i = blockIdx.x * 256 + threadIdx.x;
    int v = (i < NNODES) ? cntp[(unsigned)i << 4] : 0;
    s[threadIdx.x] = v;
    __syncthreads();
    for (int o = 1; o < 256; o <<= 1) {
        int t = (threadIdx.x >= o) ? s[threadIdx.x - o] : 0;
        __syncthreads();
        s[threadIdx.x] += t;
        __syncthreads();
    }
    if (i < NNODES) off[i] = s[threadIdx.x] - v;           // exclusive
    if (threadIdx.x == 255) bsum[blockIdx.x] = s[255];     // inclusive total
}

__global__ void k_scan2(int* __restrict__ bsum) {
    __shared__ int s[256];
    __shared__ int carry;
    if (threadIdx.x == 0) carry = 0;
    __syncthreads();
    for (int base = 0; base < SCAN_NB; base += 256) {
        int i = base + threadIdx.x;
        int v = (i < SCAN_NB) ? bsum[i] : 0;
        s[threadIdx.x] = v;
        __syncthreads();
        for (int o = 1; o < 256; o <<= 1) {
            int t = (threadIdx.x >= o) ? s[threadIdx.x - o] : 0;
            __syncthreads();
            s[threadIdx.x] += t;
            __syncthreads();
        }
        if (i < SCAN_NB) bsum[i] = s[threadIdx.x] - v + carry;
        __syncthreads();
        if (threadIdx.x == 0) carry += s[255];
        __syncthreads();
    }
}

__global__ void k_scan3(int* __restrict__ off, const int* __restrict__ bscan,
                        int* __restrict__ wposp) {
    int i = blockIdx.x * 256 + threadIdx.x;
    if (i < NNODES) {
        int v = off[i] + bscan[blockIdx.x];
        off[i] = v;
        wposp[(unsigned)i << 4] = v;      // padded write cursor (1 per line)
    }
    if (i == 0) off[NNODES] = NEDGES;     // sentinel: spmm reads off[n+1]
}

// ---------------- windowed fill (padded wpos atomics) ----------------

__global__ void k_fill_win(const int* __restrict__ src, const int4* __restrict__ dst4,
                           const float* __restrict__ w, int* __restrict__ wposp,
                           int2* __restrict__ edata) {
    const int W = (NNODES + NPASS - 1) / NPASS;
    for (int k = 0; k < NPASS; ++k) {
        int lo = k * W;
        int hi = lo + W;
        for (int i = blockIdx.x * 256 + threadIdx.x; i < NEDGES / 4;
             i += FILL_BLOCKS * 256) {
            int4 d = dst4[i];
            int e = i * 4;
            if (d.x >= lo && d.x < hi) {
                int p = atomicAdd(&wposp[(unsigned)d.x << 4], 1);
                edata[p] = make_int2(src[e], __float_as_int(w[e]));
            }
            if (d.y >= lo && d.y < hi) {
                int p = atomicAdd(&wposp[(unsigned)d.y << 4], 1);
                edata[p] = make_int2(src[e + 1], __float_as_int(w[e + 1]));
            }
            if (d.z >= lo && d.z < hi) {
                int p = atomicAdd(&wposp[(unsigned)d.z << 4], 1);
                edata[p] = make_int2(src[e + 2], __float_as_int(w[e + 2]));
            }
            if (d.w >= lo && d.w < hi) {
                int p = atomicAdd(&wposp[(unsigned)d.w << 4], 1);
                edata[p] = make_int2(src[e + 3], __float_as_int(w[e + 3]));
            }
        }
    }
}

// ---------------- gather SpMM (R1-measured v2: batch-16, persistent) ----------
// Measured optimum of this structure: 106us, 309MB L2-miss traffic @ ~3 TB/s
// -> within ~25% of fetch-time floor. Do not re-schedule (v3/v4 lessons).

__device__ __forceinline__ float4 bfrow(const ushort4* __restrict__ xb4, int s, int l16) {
    const ushort4* p = (const ushort4*)((const char*)xb4 +
                       (((unsigned)s << 7) + ((unsigned)l16 << 3)));
    ushort4 h = *p;
    float4 v;
    v.x = bf2f(h.x); v.y = bf2f(h.y); v.z = bf2f(h.z); v.w = bf2f(h.w);
    return v;
}

__device__ __forceinline__ int2 ld_edge(const int2* __restrict__ e, int i) {
    return *(const int2*)((const char*)e + ((unsigned)i << 3));
}

__global__ __launch_bounds__(256, 8)
void k_spmm1(const ushort4* __restrict__ xb4, const int* __restrict__ off,
             const int2* __restrict__ edata, ushort4* __restrict__ x1b4) {
    const int wid  = threadIdx.x >> 6;
    const int lane = threadIdx.x & 63;
    const int q    = lane >> 4;          // edge slot 0..3
    const int l16  = lane & 15;          // 16 lanes x ushort4 = 64 dims
    int n = blockIdx.x * 4 + wid;
    int o0 = off[n];
    int o1 = off[n + 1];
    while (n < NNODES) {
        int nn = n + SPMM_STRIDE;
        int no0 = 0, no1 = 0;
        if (nn < NNODES) { no0 = off[nn]; no1 = off[nn + 1]; }  // prefetch
        int deg = o1 - o0;
        int cap = o1 - 1; if (cap < 0) cap = 0;
        int b0 = o0 + q;
        int p0 = b0;      if (p0 > cap) p0 = cap;
        int p1 = b0 + 4;  if (p1 > cap) p1 = cap;
        int p2 = b0 + 8;  if (p2 > cap) p2 = cap;
        int p3 = b0 + 12; if (p3 > cap) p3 = cap;
        int2 e0 = ld_edge(edata, p0);
        int2 e1 = ld_edge(edata, p1);
        int2 e2 = ld_edge(edata, p2);
        int2 e3 = ld_edge(edata, p3);
        float4 v0 = make_float4(0.f, 0.f, 0.f, 0.f);
        float4 v1 = v0, v2 = v0, v3 = v0;
        if (q < deg)      v0 = bfrow(xb4, e0.x, l16);
        if (q + 4 < deg)  v1 = bfrow(xb4, e1.x, l16);
        if (q + 8 < deg)  v2 = bfrow(xb4, e2.x, l16);
        if (q + 12 < deg) v3 = bfrow(xb4, e3.x, l16);
        float w0 = __int_as_float(e0.y), w1 = __int_as_float(e1.y);
        float w2 = __int_as_float(e2.y), w3 = __int_as_float(e3.y);
        float4 a0, a1;
        a0.x = w0 * v0.x; a0.y = w0 * v0.y; a0.z = w0 * v0.z; a0.w = w0 * v0.w;
        a1.x = w1 * v1.x; a1.y = w1 * v1.y; a1.z = w1 * v1.z; a1.w = w1 * v1.w;
        a0.x += w2 * v2.x; a0.y += w2 * v2.y; a0.z += w2 * v2.z; a0.w += w2 * v2.w;
        a1.x += w3 * v3.x; a1.y += w3 * v3.y; a1.z += w3 * v3.z; a1.w += w3 * v3.w;
        if (deg > 16) {                       // rare tail (P ~ 0.04%)
            for (int p = b0 + 16; p < o1; p += 4) {
                int2 e = ld_edge(edata, p);
                float4 v = bfrow(xb4, e.x, l16);
                float w = __int_as_float(e.y);
                a0.x += w * v.x; a0.y += w * v.y; a0.z += w * v.z; a0.w += w * v.w;
            }
        }
        a0.x += a1.x; a0.y += a1.y; a0.z += a1.z; a0.w += a1.w;
        a0.x += __shfl_xor(a0.x, 16, 64); a0.y += __shfl_xor(a0.y, 16, 64);
        a0.z += __shfl_xor(a0.z, 16, 64); a0.w += __shfl_xor(a0.w, 16, 64);
        a0.x += __shfl_xor(a0.x, 32, 64); a0.y += __shfl_xor(a0.y, 32, 64);
        a0.z += __shfl_xor(a0.z, 32, 64); a0.w += __shfl_xor(a0.w, 32, 64);
        if (q == 0) {
            ushort4 h;
            h.x = f2bf(a0.x); h.y = f2bf(a0.y); h.z = f2bf(a0.z); h.w = f2bf(a0.w);
            x1b4[(size_t)n * 16 + l16] = h;
        }
        n = nn; o0 = no0; o1 = no1;
    }
}

__global__ __launch_bounds__(256, 8)
void k_spmm2(const float4* __restrict__ uq, const float4* __restrict__ iq,
             const ushort4* __restrict__ x1b4, const int* __restrict__ off,
             const int2* __restrict__ edata, float4* __restrict__ outq) {
    const int wid  = threadIdx.x >> 6;
    const int lane = threadIdx.x & 63;
    const int q    = lane >> 4;
    const int l16  = lane & 15;
    int n = blockIdx.x * 4 + wid;
    int o0 = off[n];
    int o1 = off[n + 1];
    while (n < NNODES) {
        int nn = n + SPMM_STRIDE;
        int no0 = 0, no1 = 0;
        if (nn < NNODES) { no0 = off[nn]; no1 = off[nn + 1]; }
        int deg = o1 - o0;
        int cap = o1 - 1; if (cap < 0) cap = 0;
        int b0 = o0 + q;
        int p0 = b0;      if (p0 > cap) p0 = cap;
        int p1 = b0 + 4;  if (p1 > cap) p1 = cap;
        int p2 = b0 + 8;  if (p2 > cap) p2 = cap;
        int p3 = b0 + 12; if (p3 > cap) p3 = cap;
        int2 e0 = ld_edge(edata, p0);
        int2 e1 = ld_edge(edata, p1);
        int2 e2 = ld_edge(edata, p2);
        int2 e3 = ld_edge(edata, p3);
        float4 v0 = make_float4(0.f, 0.f, 0.f, 0.f);
        float4 v1 = v0, v2 = v0, v3 = v0;
        if (q < deg)      v0 = bfrow(x1b4, e0.x, l16);
        if (q + 4 < deg)  v1 = bfrow(x1b4, e1.x, l16);
        if (q + 8 < deg)  v2 = bfrow(x1b4, e2.x, l16);
        if (q + 12 < deg) v3 = bfrow(x1b4, e3.x, l16);
        float w0 = __int_as_float(e0.y), w1 = __int_as_float(e1.y);
        float w2 = __int_as_float(e2.y), w3 = __int_as_float(e3.y);
        float4 a0, a1;
        a0.x = w0 * v0.x; a0.y = w0 * v0.y; a0.z = w0 * v0.z; a0.w = w0 * v0.w;
        a1.x = w1 * v1.x; a1.y = w1 * v1.y; a1.z = w1 * v1.z; a1.w = w1 * v1.w;
        a0.x += w2 * v2.x; a0.y += w2 * v2.y; a0.z += w2 * v2.z; a0.w += w2 * v2.w;
        a1.x += w3 * v3.x; a1.y += w3 * v3.y; a1.z += w3 * v3.z; a1.w += w3 * v3.w;
        if (deg > 16) {
            for (int p = b0 + 16; p < o1; p += 4) {
                int2 e = ld_edge(edata, p);
                float4 v = bfrow(x1b4, e.x, l16);
                float w = __int_as_float(e.y);
                a0.x += w * v.x; a0.y += w * v.y; a0.z += w * v.z; a0.w += w * v.w;
            }
        }
        a0.x += a1.x; a0.y += a1.y; a0.z += a1.z; a0.w += a1.w;
        a0.x += __shfl_xor(a0.x, 16, 64); a0.y += __shfl_xor(a0.y, 16, 64);
        a0.z += __shfl_xor(a0.z, 16, 64); a0.w += __shfl_xor(a0.w, 16, 64);
        a0.x += __shfl_xor(a0.x, 32, 64); a0.y += __shfl_xor(a0.y, 32, 64);
        a0.z += __shfl_xor(a0.z, 32, 64); a0.w += __shfl_xor(a0.w, 32, 64);
        if (q == 0) {
            size_t ridx = (size_t)n * 16 + l16;
            float4 x0 = (n < NUSERS) ? uq[ridx] : iq[ridx - (size_t)NUSERS * 16];
            float4 x1v = bfrow(x1b4, n, l16);
            const float s = 1.0f / 3.0f;
            float4 r;
            r.x = (x0.x + x1v.x + a0.x) * s;
            r.y = (x0.y + x1v.y + a0.y) * s;
            r.z = (x0.z + x1v.z + a0.z) * s;
            r.w = (x0.w + x1v.w + a0.w) * s;
            outq[ridx] = r;
        }
        n = nn; o0 = no0; o1 = no1;
    }
}

// ---------------- fallback (atomic path, if ws too small) ----------------

__global__ void scatter_l1(const float* __restrict__ u, const float* __restrict__ it,
                           float* __restrict__ y,
                           const int* __restrict__ src, const int* __restrict__ dst,
                           const float* __restrict__ w) {
    long long t = (long long)blockIdx.x * blockDim.x + threadIdx.x;
    int e = (int)(t >> 4);
    if (e >= NEDGES) return;
    int q = (int)(t & 15);
    int s = src[e], d = dst[e];
    float we = w[e];
    const float* xrow = (s < NUSERS) ? (u + (size_t)s * EDIM)
                                     : (it + (size_t)(s - NUSERS) * EDIM);
    float4 v = ((const float4*)xrow)[q];
    float* yp = y + (size_t)d * EDIM + q * 4;
    atomicAdd(yp + 0, we * v.x);
    atomicAdd(yp + 1, we * v.y);
    atomicAdd(yp + 2, we * v.z);
    atomicAdd(yp + 3, we * v.w);
}

__global__ void scatter_gen(const float* __restrict__ x, float* __restrict__ y,
                            const int* __restrict__ src, const int* __restrict__ dst,
                            const float* __restrict__ w) {
    long long t = (long long)blockIdx.x * blockDim.x + threadIdx.x;
    int e = (int)(t >> 4);
    if (e >= NEDGES) return;
    int q = (int)(t & 15);
    int s = src[e], d = dst[e];
    float we = w[e];
    float4 v = ((const float4*)(x + (size_t)s * EDIM))[q];
    float* yp = y + (size_t)d * EDIM + q * 4;
    atomicAdd(yp + 0, we * v.x);
    atomicAdd(yp + 1, we * v.y);
    atomicAdd(yp + 2, we * v.z);
    atomicAdd(yp + 3, we * v.w);
}

__global__ void final_kernel(const float4* __restrict__ u, const float4* __restrict__ it,
                             const float4* __restrict__ x2, float4* __restrict__ outq) {
    int i = blockIdx.x * blockDim.x + threadIdx.x;
    const int uq = NUSERS * EDIM / 4;
    const int nq = NNODES * EDIM / 4;
    if (i >= nq) return;
    float4 x0 = (i < uq) ? u[i] : it[i - uq];
    float4 x1 = outq[i];
    float4 a  = x2[i];
    const float s = 1.0f / 3.0f;
    float4 r;
    r.x = (x0.x + x1.x + a.x) * s;
    r.y = (x0.y + x1.y + a.y) * s;
    r.z = (x0.z + x1.z + a.z) * s;
    r.w = (x0.w + x1.w + a.w) * s;
    outq[i] = r;
}

// ---------------- launch ----------------

extern "C" void kernel_launch(void* const* d_in, const int* in_sizes, int n_in,
                              void* d_out, int out_size, void* d_ws, size_t ws_size,
                              hipStream_t stream) {
    const float* u   = (const float*)d_in[0];
    const float* it  = (const float*)d_in[1];
    const int*   src = (const int*)d_in[2];
    const int*   dst = (const int*)d_in[3];
    const float* w   = (const float*)d_in[4];
    float* out = (float*)d_out;

    const size_t nd = (size_t)NNODES * EDIM;

    // ws layout (full path) — off has +8 pad for the off[NNODES] sentinel.
    // The 19.2 MB padded counter buffer (cntp, reused as wposp) ALIASES the
    // x1b4 region: lifetime-disjoint (cntp/wposp dead after k_fill_win;
    // x1b4 first written by k_spmm1 which launches after).
    int*     off   = (int*)d_ws;                 // NNODES+8
    int*     bscan = off + NNODES + 8;           // 2048 (>= SCAN_NB)
    int2*    edata = (int2*)(bscan + 2048);      // NEDGES packed (src, w)
    ushort4* xb4   = (ushort4*)(edata + NEDGES); // NNODES*16 (bf16 x0)
    ushort4* x1b4  = xb4 + (size_t)NNODES * 16;  // NNODES*16 (bf16 x1)
    int*     cntp  = (int*)x1b4;                 // NNODES*CPAD ints (19.2 MB, aliased)
    const size_t needed =
        (size_t)(NNODES + 8 + 2048) * sizeof(int) +
        (size_t)NEDGES * sizeof(int2) +
        (size_t)NNODES * 16 * sizeof(ushort4) * 2;

    dim3 blk(256);

    if (ws_size >= needed) {
        // --- CSR counts (padded) + bf16 convert (fused) ---
        hipMemsetAsync(cntp, 0, (size_t)NNODES * CPAD * sizeof(int), stream);
        k_prep <<<PREP_HB + PREP_CB, blk, 0, stream>>>((const int4*)dst, cntp,
                                              (const float4*)u, (const float4*)it, xb4);
        k_scan1<<<SCAN_NB, blk, 0, stream>>>(cntp, off, bscan);
        k_scan2<<<1, blk, 0, stream>>>(bscan);
        k_scan3<<<SCAN_NB, blk, 0, stream>>>(off, bscan, cntp);   // cntp -> wposp
        k_fill_win<<<FILL_BLOCKS, blk, 0, stream>>>(src, (const int4*)dst, w, cntp, edata);
        // --- layer 1: x1b = bf16(A @ xb)  (overwrites cntp/wposp region) ---
        k_spmm1<<<SPMM_BLOCKS, blk, 0, stream>>>(xb4, off, edata, x1b4);
        // --- layer 2 + epilogue: out = (x0 + x1 + A@x1)/3 ---
        k_spmm2<<<SPMM_BLOCKS, blk, 0, stream>>>((const float4*)u, (const float4*)it,
                                                 x1b4, off, edata, (float4*)out);
    } else {
        // fallback: atomic scatter path (requires only 76.8 MB ws)
        float* A = (float*)d_ws;
        hipMemsetAsync(out, 0, nd * sizeof(float), stream);
        long long nthreads = (long long)NEDGES * 16;
        int sblocks = (int)((nthreads + 255) / 256);
        scatter_l1<<<sblocks, blk, 0, stream>>>(u, it, out, src, dst, w);
        hipMemsetAsync(A, 0, nd * sizeof(float), stream);
        scatter_gen<<<sblocks, blk, 0, stream>>>(out, A, src, dst, w);
        final_kernel<<<(NNODES * EDIM / 4 + 255) / 256, blk, 0, stream>>>(
            (const float4*)u, (const float4*)it, (const float4*)A, (float4*)out);
    }
}

// Round 6
// 441.034 us; speedup vs baseline: 1.2048x; 1.2048x over previous
//
#include <hip/hip_runtime.h>
#include <hip/hip_bf16.h>

#define NUSERS 200000
#define NITEMS 100000
#define NNODES 300000
#define EDIM   64
#define NEDGES 2000000
#define SCAN_NB ((NNODES + 255) / 256)   // 1172 blocks
#define FILL_BLOCKS 2048
#define NPASS 4
#define PREP_HB 2048                     // CSR-path hist blocks (grid-stride)
#define PREP_CB 2048                     // convert blocks (grid-stride)
#define SPMM_BLOCKS 2048                 // 8 blocks/CU persistent
#define SPMM_STRIDE (SPMM_BLOCKS * 4)    // one node per wave per sweep
#define CPAD 16                          // CSR-path counter padding
#define CAP  32                          // bucket capacity (P(deg>32) ~ 3e-7)

typedef unsigned short u16;

__device__ __forceinline__ float bf2f(u16 h) {
    return __uint_as_float((unsigned)h << 16);
}
__device__ __forceinline__ u16 f2bf(float f) {
    union { __hip_bfloat16 b; u16 u; } c;
    c.b = __float2bfloat16(f);   // RNE
    return c.u;
}

// =================== BUCKET PATH (primary) ===================
// R5 post-mortem: hist cost is invariant to grid shape AND counter padding
// at VALU 1.4% -> device-atomic throughput ceiling (~18G/s at the XCD
// coherence point). So: ONE atomic pass, not two. Bucket CSR: slot from the
// counting atomic itself; no scan, no separate fill.

// fused windowed bucket-fill + bf16 convert
__global__ void k_prep2(const int* __restrict__ src, const int4* __restrict__ dst4,
                        const float* __restrict__ w, int* __restrict__ cnt,
                        int2* __restrict__ bedata,
                        const float4* __restrict__ uq, const float4* __restrict__ iq,
                        ushort4* __restrict__ xb4) {
    int b = blockIdx.x;
    if (b < FILL_BLOCKS) {
        // windowed so concurrent bucket writes cluster into a 19.2MB region
        const int W = (NNODES + NPASS - 1) / NPASS;
        for (int k = 0; k < NPASS; ++k) {
            int lo = k * W;
            int hi = lo + W;
            for (int i = b * 256 + threadIdx.x; i < NEDGES / 4;
                 i += FILL_BLOCKS * 256) {
                int4 d = dst4[i];
                int e = i * 4;
                if (d.x >= lo && d.x < hi) {
                    int p = atomicAdd(&cnt[d.x], 1);
                    if (p < CAP) bedata[(unsigned)d.x * CAP + p] =
                        make_int2(src[e], __float_as_int(w[e]));
                }
                if (d.y >= lo && d.y < hi) {
                    int p = atomicAdd(&cnt[d.y], 1);
                    if (p < CAP) bedata[(unsigned)d.y * CAP + p] =
                        make_int2(src[e + 1], __float_as_int(w[e + 1]));
                }
                if (d.z >= lo && d.z < hi) {
                    int p = atomicAdd(&cnt[d.z], 1);
                    if (p < CAP) bedata[(unsigned)d.z * CAP + p] =
                        make_int2(src[e + 2], __float_as_int(w[e + 2]));
                }
                if (d.w >= lo && d.w < hi) {
                    int p = atomicAdd(&cnt[d.w], 1);
                    if (p < CAP) bedata[(unsigned)d.w * CAP + p] =
                        make_int2(src[e + 3], __float_as_int(w[e + 3]));
                }
            }
        }
    } else {
        for (int i = (b - FILL_BLOCKS) * 256 + threadIdx.x; i < NNODES * 16;
             i += PREP_CB * 256) {
            float4 v = (i < NUSERS * 16) ? uq[i] : iq[i - NUSERS * 16];
            ushort4 h;
            h.x = f2bf(v.x); h.y = f2bf(v.y); h.z = f2bf(v.z); h.w = f2bf(v.w);
            xb4[i] = h;
        }
    }
}

__device__ __forceinline__ float4 bfrow(const ushort4* __restrict__ xb4, int s, int l16) {
    const ushort4* p = (const ushort4*)((const char*)xb4 +
                       (((unsigned)s << 7) + ((unsigned)l16 << 3)));
    ushort4 h = *p;
    float4 v;
    v.x = bf2f(h.x); v.y = bf2f(h.y); v.z = bf2f(h.z); v.w = bf2f(h.w);
    return v;
}

__device__ __forceinline__ int2 ld_edge(const int2* __restrict__ e, unsigned i) {
    return *(const int2*)((const char*)e + (i << 3));
}

// bucket SpMM: same measured-optimal batch-16 structure as CSR v2, but
// deg from cnt[n], edges at fixed base n*CAP. Slot-clamped (locality) +
// weight zero-select (deg==0 reads garbage slot0 -> must not NaN-poison).
__global__ __launch_bounds__(256, 8)
void k_spmm1b(const ushort4* __restrict__ xb4, const int* __restrict__ cnt,
              const int2* __restrict__ bedata, ushort4* __restrict__ x1b4) {
    const int wid  = threadIdx.x >> 6;
    const int lane = threadIdx.x & 63;
    const int q    = lane >> 4;          // edge slot 0..3
    const int l16  = lane & 15;          // 16 lanes x ushort4 = 64 dims
    int n = blockIdx.x * 4 + wid;
    int dc = cnt[n];
    while (n < NNODES) {
        int nn = n + SPMM_STRIDE;
        int dn = 0;
        if (nn < NNODES) dn = cnt[nn];   // prefetch next sweep's count
        int deg = (dc < CAP) ? dc : CAP;
        int capi = deg - 1; if (capi < 0) capi = 0;
        unsigned base = (unsigned)n * CAP;
        int s0 = q;      if (s0 > capi) s0 = capi;
        int s1 = q + 4;  if (s1 > capi) s1 = capi;
        int s2 = q + 8;  if (s2 > capi) s2 = capi;
        int s3 = q + 12; if (s3 > capi) s3 = capi;
        int2 e0 = ld_edge(bedata, base + s0);
        int2 e1 = ld_edge(bedata, base + s1);
        int2 e2 = ld_edge(bedata, base + s2);
        int2 e3 = ld_edge(bedata, base + s3);
        float4 v0 = make_float4(0.f, 0.f, 0.f, 0.f);
        float4 v1 = v0, v2 = v0, v3 = v0;
        if (q < deg)      v0 = bfrow(xb4, e0.x, l16);
        if (q + 4 < deg)  v1 = bfrow(xb4, e1.x, l16);
        if (q + 8 < deg)  v2 = bfrow(xb4, e2.x, l16);
        if (q + 12 < deg) v3 = bfrow(xb4, e3.x, l16);
        float w0 = (q < deg)      ? __int_as_float(e0.y) : 0.f;
        float w1 = (q + 4 < deg)  ? __int_as_float(e1.y) : 0.f;
        float w2 = (q + 8 < deg)  ? __int_as_float(e2.y) : 0.f;
        float w3 = (q + 12 < deg) ? __int_as_float(e3.y) : 0.f;
        float4 a0, a1;
        a0.x = w0 * v0.x; a0.y = w0 * v0.y; a0.z = w0 * v0.z; a0.w = w0 * v0.w;
        a1.x = w1 * v1.x; a1.y = w1 * v1.y; a1.z = w1 * v1.z; a1.w = w1 * v1.w;
        a0.x += w2 * v2.x; a0.y += w2 * v2.y; a0.z += w2 * v2.z; a0.w += w2 * v2.w;
        a1.x += w3 * v3.x; a1.y += w3 * v3.y; a1.z += w3 * v3.z; a1.w += w3 * v3.w;
        if (deg > 16) {                       // rare tail
            for (int s = q + 16; s < deg; s += 4) {
                int2 e = ld_edge(bedata, base + s);
                float4 v = bfrow(xb4, e.x, l16);
                float w = __int_as_float(e.y);
                a0.x += w * v.x; a0.y += w * v.y; a0.z += w * v.z; a0.w += w * v.w;
            }
        }
        a0.x += a1.x; a0.y += a1.y; a0.z += a1.z; a0.w += a1.w;
        a0.x += __shfl_xor(a0.x, 16, 64); a0.y += __shfl_xor(a0.y, 16, 64);
        a0.z += __shfl_xor(a0.z, 16, 64); a0.w += __shfl_xor(a0.w, 16, 64);
        a0.x += __shfl_xor(a0.x, 32, 64); a0.y += __shfl_xor(a0.y, 32, 64);
        a0.z += __shfl_xor(a0.z, 32, 64); a0.w += __shfl_xor(a0.w, 32, 64);
        if (q == 0) {
            ushort4 h;
            h.x = f2bf(a0.x); h.y = f2bf(a0.y); h.z = f2bf(a0.z); h.w = f2bf(a0.w);
            x1b4[(size_t)n * 16 + l16] = h;
        }
        n = nn; dc = dn;
    }
}

__global__ __launch_bounds__(256, 8)
void k_spmm2b(const float4* __restrict__ uq, const float4* __restrict__ iq,
              const ushort4* __restrict__ x1b4, const int* __restrict__ cnt,
              const int2* __restrict__ bedata, float4* __restrict__ outq) {
    const int wid  = threadIdx.x >> 6;
    const int lane = threadIdx.x & 63;
    const int q    = lane >> 4;
    const int l16  = lane & 15;
    int n = blockIdx.x * 4 + wid;
    int dc = cnt[n];
    while (n < NNODES) {
        int nn = n + SPMM_STRIDE;
        int dn = 0;
        if (nn < NNODES) dn = cnt[nn];
        int deg = (dc < CAP) ? dc : CAP;
        int capi = deg - 1; if (capi < 0) capi = 0;
        unsigned base = (unsigned)n * CAP;
        int s0 = q;      if (s0 > capi) s0 = capi;
        int s1 = q + 4;  if (s1 > capi) s1 = capi;
        int s2 = q + 8;  if (s2 > capi) s2 = capi;
        int s3 = q + 12; if (s3 > capi) s3 = capi;
        int2 e0 = ld_edge(bedata, base + s0);
        int2 e1 = ld_edge(bedata, base + s1);
        int2 e2 = ld_edge(bedata, base + s2);
        int2 e3 = ld_edge(bedata, base + s3);
        float4 v0 = make_float4(0.f, 0.f, 0.f, 0.f);
        float4 v1 = v0, v2 = v0, v3 = v0;
        if (q < deg)      v0 = bfrow(x1b4, e0.x, l16);
        if (q + 4 < deg)  v1 = bfrow(x1b4, e1.x, l16);
        if (q + 8 < deg)  v2 = bfrow(x1b4, e2.x, l16);
        if (q + 12 < deg) v3 = bfrow(x1b4, e3.x, l16);
        float w0 = (q < deg)      ? __int_as_float(e0.y) : 0.f;
        float w1 = (q + 4 < deg)  ? __int_as_float(e1.y) : 0.f;
        float w2 = (q + 8 < deg)  ? __int_as_float(e2.y) : 0.f;
        float w3 = (q + 12 < deg) ? __int_as_float(e3.y) : 0.f;
        float4 a0, a1;
        a0.x = w0 * v0.x; a0.y = w0 * v0.y; a0.z = w0 * v0.z; a0.w = w0 * v0.w;
        a1.x = w1 * v1.x; a1.y = w1 * v1.y; a1.z = w1 * v1.z; a1.w = w1 * v1.w;
        a0.x += w2 * v2.x; a0.y += w2 * v2.y; a0.z += w2 * v2.z; a0.w += w2 * v2.w;
        a1.x += w3 * v3.x; a1.y += w3 * v3.y; a1.z += w3 * v3.z; a1.w += w3 * v3.w;
        if (deg > 16) {
            for (int s = q + 16; s < deg; s += 4) {
                int2 e = ld_edge(bedata, base + s);
                float4 v = bfrow(x1b4, e.x, l16);
                float w = __int_as_float(e.y);
                a0.x += w * v.x; a0.y += w * v.y; a0.z += w * v.z; a0.w += w * v.w;
            }
        }
        a0.x += a1.x; a0.y += a1.y; a0.z += a1.z; a0.w += a1.w;
        a0.x += __shfl_xor(a0.x, 16, 64); a0.y += __shfl_xor(a0.y, 16, 64);
        a0.z += __shfl_xor(a0.z, 16, 64); a0.w += __shfl_xor(a0.w, 16, 64);
        a0.x += __shfl_xor(a0.x, 32, 64); a0.y += __shfl_xor(a0.y, 32, 64);
        a0.z += __shfl_xor(a0.z, 32, 64); a0.w += __shfl_xor(a0.w, 32, 64);
        if (q == 0) {
            size_t ridx = (size_t)n * 16 + l16;
            float4 x0 = (n < NUSERS) ? uq[ridx] : iq[ridx - (size_t)NUSERS * 16];
            float4 x1v = bfrow(x1b4, n, l16);
            const float s = 1.0f / 3.0f;
            float4 r;
            r.x = (x0.x + x1v.x + a0.x) * s;
            r.y = (x0.y + x1v.y + a0.y) * s;
            r.z = (x0.z + x1v.z + a0.z) * s;
            r.w = (x0.w + x1v.w + a0.w) * s;
            outq[ridx] = r;
        }
        n = nn; dc = dn;
    }
}

// =================== CSR PATH (middle tier, R5-measured) ===================

__global__ void k_prep(const int4* __restrict__ dst4, int* __restrict__ cnt,
                       const float4* __restrict__ uq, const float4* __restrict__ iq,
                       ushort4* __restrict__ xb4) {
    int b = blockIdx.x;
    if (b < PREP_HB) {
        for (int i = b * 256 + threadIdx.x; i < NEDGES / 4; i += PREP_HB * 256) {
            int4 d = dst4[i];
            atomicAdd(&cnt[(unsigned)d.x << 4], 1);
            atomicAdd(&cnt[(unsigned)d.y << 4], 1);
            atomicAdd(&cnt[(unsigned)d.z << 4], 1);
            atomicAdd(&cnt[(unsigned)d.w << 4], 1);
        }
    } else {
        for (int i = (b - PREP_HB) * 256 + threadIdx.x; i < NNODES * 16;
             i += PREP_CB * 256) {
            float4 v = (i < NUSERS * 16) ? uq[i] : iq[i - NUSERS * 16];
            ushort4 h;
            h.x = f2bf(v.x); h.y = f2bf(v.y); h.z = f2bf(v.z); h.w = f2bf(v.w);
            xb4[i] = h;
        }
    }
}

__global__ void k_scan1(const int* __restrict__ cntp, int* __restrict__ off,
                        int* __restrict__ bsum) {
    __shared__ int s[256];
    int i = blockIdx.x * 256 + threadIdx.x;
    int v = (i < NNODES) ? cntp[(unsigned)i << 4] : 0;
    s[threadIdx.x] = v;
    __syncthreads();
    for (int o = 1; o < 256; o <<= 1) {
        int t = (threadIdx.x >= o) ? s[threadIdx.x - o] : 0;
        __syncthreads();
        s[threadIdx.x] += t;
        __syncthreads();
    }
    if (i < NNODES) off[i] = s[threadIdx.x] - v;
    if (threadIdx.x == 255) bsum[blockIdx.x] = s[255];
}

__global__ void k_scan2(int* __restrict__ bsum) {
    __shared__ int s[256];
    __shared__ int carry;
    if (threadIdx.x == 0) carry = 0;
    __syncthreads();
    for (int base = 0; base < SCAN_NB; base += 256) {
        int i = base + threadIdx.x;
        int v = (i < SCAN_NB) ? bsum[i] : 0;
        s[threadIdx.x] = v;
        __syncthreads();
        for (int o = 1; o < 256; o <<= 1) {
            int t = (threadIdx.x >= o) ? s[threadIdx.x - o] : 0;
            __syncthreads();
            s[threadIdx.x] += t;
            __syncthreads();
        }
        if (i < SCAN_NB) bsum[i] = s[threadIdx.x] - v + carry;
        __syncthreads();
        if (threadIdx.x == 0) carry += s[255];
        __syncthreads();
    }
}

__global__ void k_scan3(int* __restrict__ off, const int* __restrict__ bscan,
                        int* __restrict__ wposp) {
    int i = blockIdx.x * 256 + threadIdx.x;
    if (i < NNODES) {
        int v = off[i] + bscan[blockIdx.x];
        off[i] = v;
        wposp[(unsigned)i << 4] = v;
    }
    if (i == 0) off[NNODES] = NEDGES;
}

__global__ void k_fill_win(const int* __restrict__ src, const int4* __restrict__ dst4,
                           const float* __restrict__ w, int* __restrict__ wposp,
                           int2* __restrict__ edata) {
    const int W = (NNODES + NPASS - 1) / NPASS;
    for (int k = 0; k < NPASS; ++k) {
        int lo = k * W;
        int hi = lo + W;
        for (int i = blockIdx.x * 256 + threadIdx.x; i < NEDGES / 4;
             i += FILL_BLOCKS * 256) {
            int4 d = dst4[i];
            int e = i * 4;
            if (d.x >= lo && d.x < hi) {
                int p = atomicAdd(&wposp[(unsigned)d.x << 4], 1);
                edata[p] = make_int2(src[e], __float_as_int(w[e]));
            }
            if (d.y >= lo && d.y < hi) {
                int p = atomicAdd(&wposp[(unsigned)d.y << 4], 1);
                edata[p] = make_int2(src[e + 1], __float_as_int(w[e + 1]));
            }
            if (d.z >= lo && d.z < hi) {
                int p = atomicAdd(&wposp[(unsigned)d.z << 4], 1);
                edata[p] = make_int2(src[e + 2], __float_as_int(w[e + 2]));
            }
            if (d.w >= lo && d.w < hi) {
                int p = atomicAdd(&wposp[(unsigned)d.w << 4], 1);
                edata[p] = make_int2(src[e + 3], __float_as_int(w[e + 3]));
            }
        }
    }
}

__global__ __launch_bounds__(256, 8)
void k_spmm1(const ushort4* __restrict__ xb4, const int* __restrict__ off,
             const int2* __restrict__ edata, ushort4* __restrict__ x1b4) {
    const int wid  = threadIdx.x >> 6;
    const int lane = threadIdx.x & 63;
    const int q    = lane >> 4;
    const int l16  = lane & 15;
    int n = blockIdx.x * 4 + wid;
    int o0 = off[n];
    int o1 = off[n + 1];
    while (n < NNODES) {
        int nn = n + SPMM_STRIDE;
        int no0 = 0, no1 = 0;
        if (nn < NNODES) { no0 = off[nn]; no1 = off[nn + 1]; }
        int deg = o1 - o0;
        int cap = o1 - 1; if (cap < 0) cap = 0;
        int b0 = o0 + q;
        int p0 = b0;      if (p0 > cap) p0 = cap;
        int p1 = b0 + 4;  if (p1 > cap) p1 = cap;
        int p2 = b0 + 8;  if (p2 > cap) p2 = cap;
        int p3 = b0 + 12; if (p3 > cap) p3 = cap;
        int2 e0 = ld_edge(edata, p0);
        int2 e1 = ld_edge(edata, p1);
        int2 e2 = ld_edge(edata, p2);
        int2 e3 = ld_edge(edata, p3);
        float4 v0 = make_float4(0.f, 0.f, 0.f, 0.f);
        float4 v1 = v0, v2 = v0, v3 = v0;
        if (q < deg)      v0 = bfrow(xb4, e0.x, l16);
        if (q + 4 < deg)  v1 = bfrow(xb4, e1.x, l16);
        if (q + 8 < deg)  v2 = bfrow(xb4, e2.x, l16);
        if (q + 12 < deg) v3 = bfrow(xb4, e3.x, l16);
        float w0 = __int_as_float(e0.y), w1 = __int_as_float(e1.y);
        float w2 = __int_as_float(e2.y), w3 = __int_as_float(e3.y);
        float4 a0, a1;
        a0.x = w0 * v0.x; a0.y = w0 * v0.y; a0.z = w0 * v0.z; a0.w = w0 * v0.w;
        a1.x = w1 * v1.x; a1.y = w1 * v1.y; a1.z = w1 * v1.z; a1.w = w1 * v1.w;
        a0.x += w2 * v2.x; a0.y += w2 * v2.y; a0.z += w2 * v2.z; a0.w += w2 * v2.w;
        a1.x += w3 * v3.x; a1.y += w3 * v3.y; a1.z += w3 * v3.z; a1.w += w3 * v3.w;
        if (deg > 16) {
            for (int p = b0 + 16; p < o1; p += 4) {
                int2 e = ld_edge(edata, p);
                float4 v = bfrow(xb4, e.x, l16);
                float w = __int_as_float(e.y);
                a0.x += w * v.x; a0.y += w * v.y; a0.z += w * v.z; a0.w += w * v.w;
            }
        }
        a0.x += a1.x; a0.y += a1.y; a0.z += a1.z; a0.w += a1.w;
        a0.x += __shfl_xor(a0.x, 16, 64); a0.y += __shfl_xor(a0.y, 16, 64);
        a0.z += __shfl_xor(a0.z, 16, 64); a0.w += __shfl_xor(a0.w, 16, 64);
        a0.x += __shfl_xor(a0.x, 32, 64); a0.y += __shfl_xor(a0.y, 32, 64);
        a0.z += __shfl_xor(a0.z, 32, 64); a0.w += __shfl_xor(a0.w, 32, 64);
        if (q == 0) {
            ushort4 h;
            h.x = f2bf(a0.x); h.y = f2bf(a0.y); h.z = f2bf(a0.z); h.w = f2bf(a0.w);
            x1b4[(size_t)n * 16 + l16] = h;
        }
        n = nn; o0 = no0; o1 = no1;
    }
}

__global__ __launch_bounds__(256, 8)
void k_spmm2(const float4* __restrict__ uq, const float4* __restrict__ iq,
             const ushort4* __restrict__ x1b4, const int* __restrict__ off,
             const int2* __restrict__ edata, float4* __restrict__ outq) {
    const int wid  = threadIdx.x >> 6;
    const int lane = threadIdx.x & 63;
    const int q    = lane >> 4;
    const int l16  = lane & 15;
    int n = blockIdx.x * 4 + wid;
    int o0 = off[n];
    int o1 = off[n + 1];
    while (n < NNODES) {
        int nn = n + SPMM_STRIDE;
        int no0 = 0, no1 = 0;
        if (nn < NNODES) { no0 = off[nn]; no1 = off[nn + 1]; }
        int deg = o1 - o0;
        int cap = o1 - 1; if (cap < 0) cap = 0;
        int b0 = o0 + q;
        int p0 = b0;      if (p0 > cap) p0 = cap;
        int p1 = b0 + 4;  if (p1 > cap) p1 = cap;
        int p2 = b0 + 8;  if (p2 > cap) p2 = cap;
        int p3 = b0 + 12; if (p3 > cap) p3 = cap;
        int2 e0 = ld_edge(edata, p0);
        int2 e1 = ld_edge(edata, p1);
        int2 e2 = ld_edge(edata, p2);
        int2 e3 = ld_edge(edata, p3);
        float4 v0 = make_float4(0.f, 0.f, 0.f, 0.f);
        float4 v1 = v0, v2 = v0, v3 = v0;
        if (q < deg)      v0 = bfrow(x1b4, e0.x, l16);
        if (q + 4 < deg)  v1 = bfrow(x1b4, e1.x, l16);
        if (q + 8 < deg)  v2 = bfrow(x1b4, e2.x, l16);
        if (q + 12 < deg) v3 = bfrow(x1b4, e3.x, l16);
        float w0 = __int_as_float(e0.y), w1 = __int_as_float(e1.y);
        float w2 = __int_as_float(e2.y), w3 = __int_as_float(e3.y);
        float4 a0, a1;
        a0.x = w0 * v0.x; a0.y = w0 * v0.y; a0.z = w0 * v0.z; a0.w = w0 * v0.w;
        a1.x = w1 * v1.x; a1.y = w1 * v1.y; a1.z = w1 * v1.z; a1.w = w1 * v1.w;
        a0.x += w2 * v2.x; a0.y += w2 * v2.y; a0.z += w2 * v2.z; a0.w += w2 * v2.w;
        a1.x += w3 * v3.x; a1.y += w3 * v3.y; a1.z += w3 * v3.z; a1.w += w3 * v3.w;
        if (deg > 16) {
            for (int p = b0 + 16; p < o1; p += 4) {
                int2 e = ld_edge(edata, p);
                float4 v = bfrow(x1b4, e.x, l16);
                float w = __int_as_float(e.y);
                a0.x += w * v.x; a0.y += w * v.y; a0.z += w * v.z; a0.w += w * v.w;
            }
        }
        a0.x += a1.x; a0.y += a1.y; a0.z += a1.z; a0.w += a1.w;
        a0.x += __shfl_xor(a0.x, 16, 64); a0.y += __shfl_xor(a0.y, 16, 64);
        a0.z += __shfl_xor(a0.z, 16, 64); a0.w += __shfl_xor(a0.w, 16, 64);
        a0.x += __shfl_xor(a0.x, 32, 64); a0.y += __shfl_xor(a0.y, 32, 64);
        a0.z += __shfl_xor(a0.z, 32, 64); a0.w += __shfl_xor(a0.w, 32, 64);
        if (q == 0) {
            size_t ridx = (size_t)n * 16 + l16;
            float4 x0 = (n < NUSERS) ? uq[ridx] : iq[ridx - (size_t)NUSERS * 16];
            float4 x1v = bfrow(x1b4, n, l16);
            const float s = 1.0f / 3.0f;
            float4 r;
            r.x = (x0.x + x1v.x + a0.x) * s;
            r.y = (x0.y + x1v.y + a0.y) * s;
            r.z = (x0.z + x1v.z + a0.z) * s;
            r.w = (x0.w + x1v.w + a0.w) * s;
            outq[ridx] = r;
        }
        n = nn; o0 = no0; o1 = no1;
    }
}

// ---------------- fallback (atomic path, if ws too small) ----------------

__global__ void scatter_l1(const float* __restrict__ u, const float* __restrict__ it,
                           float* __restrict__ y,
                           const int* __restrict__ src, const int* __restrict__ dst,
                           const float* __restrict__ w) {
    long long t = (long long)blockIdx.x * blockDim.x + threadIdx.x;
    int e = (int)(t >> 4);
    if (e >= NEDGES) return;
    int q = (int)(t & 15);
    int s = src[e], d = dst[e];
    float we = w[e];
    const float* xrow = (s < NUSERS) ? (u + (size_t)s * EDIM)
                                     : (it + (size_t)(s - NUSERS) * EDIM);
    float4 v = ((const float4*)xrow)[q];
    float* yp = y + (size_t)d * EDIM + q * 4;
    atomicAdd(yp + 0, we * v.x);
    atomicAdd(yp + 1, we * v.y);
    atomicAdd(yp + 2, we * v.z);
    atomicAdd(yp + 3, we * v.w);
}

__global__ void scatter_gen(const float* __restrict__ x, float* __restrict__ y,
                            const int* __restrict__ src, const int* __restrict__ dst,
                            const float* __restrict__ w) {
    long long t = (long long)blockIdx.x * blockDim.x + threadIdx.x;
    int e = (int)(t >> 4);
    if (e >= NEDGES) return;
    int q = (int)(t & 15);
    int s = src[e], d = dst[e];
    float we = w[e];
    float4 v = ((const float4*)(x + (size_t)s * EDIM))[q];
    float* yp = y + (size_t)d * EDIM + q * 4;
    atomicAdd(yp + 0, we * v.x);
    atomicAdd(yp + 1, we * v.y);
    atomicAdd(yp + 2, we * v.z);
    atomicAdd(yp + 3, we * v.w);
}

__global__ void final_kernel(const float4* __restrict__ u, const float4* __restrict__ it,
                             const float4* __restrict__ x2, float4* __restrict__ outq) {
    int i = blockIdx.x * blockDim.x + threadIdx.x;
    const int uq = NUSERS * EDIM / 4;
    const int nq = NNODES * EDIM / 4;
    if (i >= nq) return;
    float4 x0 = (i < uq) ? u[i] : it[i - uq];
    float4 x1 = outq[i];
    float4 a  = x2[i];
    const float s = 1.0f / 3.0f;
    float4 r;
    r.x = (x0.x + x1.x + a.x) * s;
    r.y = (x0.y + x1.y + a.y) * s;
    r.z = (x0.z + x1.z + a.z) * s;
    r.w = (x0.w + x1.w + a.w) * s;
    outq[i] = r;
}

// ---------------- launch ----------------

extern "C" void kernel_launch(void* const* d_in, const int* in_sizes, int n_in,
                              void* d_out, int out_size, void* d_ws, size_t ws_size,
                              hipStream_t stream) {
    const float* u   = (const float*)d_in[0];
    const float* it  = (const float*)d_in[1];
    const int*   src = (const int*)d_in[2];
    const int*   dst = (const int*)d_in[3];
    const float* w   = (const float*)d_in[4];
    float* out = (float*)d_out;

    const size_t nd = (size_t)NNODES * EDIM;
    dim3 blk(256);

    // ---- bucket-path layout (~155 MB) ----
    int*     bcnt    = (int*)d_ws;                       // NNODES (+512 align pad)
    int2*    bedata  = (int2*)(bcnt + NNODES + 512);     // NNODES*CAP
    ushort4* bxb4    = (ushort4*)(bedata + (size_t)NNODES * CAP);
    ushort4* bx1b4   = bxb4 + (size_t)NNODES * 16;
    const size_t need_bucket =
        (size_t)(NNODES + 512) * sizeof(int) +
        (size_t)NNODES * CAP * sizeof(int2) +
        (size_t)NNODES * 16 * sizeof(ushort4) * 2;

    // ---- CSR-path layout (~94 MB; cntp/wposp aliases x1b4, lifetime-disjoint) ----
    int*     off   = (int*)d_ws;                 // NNODES+8
    int*     bscan = off + NNODES + 8;           // 2048
    int2*    edata = (int2*)(bscan + 2048);      // NEDGES
    ushort4* xb4   = (ushort4*)(edata + NEDGES); // NNODES*16
    ushort4* x1b4  = xb4 + (size_t)NNODES * 16;  // NNODES*16
    int*     cntp  = (int*)x1b4;                 // NNODES*CPAD (aliased)
    const size_t need_csr =
        (size_t)(NNODES + 8 + 2048) * sizeof(int) +
        (size_t)NEDGES * sizeof(int2) +
        (size_t)NNODES * 16 * sizeof(ushort4) * 2;

    if (ws_size >= need_bucket) {
        // --- single atomic pass: bucket fill + convert fused ---
        hipMemsetAsync(bcnt, 0, (size_t)NNODES * sizeof(int), stream);
        k_prep2<<<FILL_BLOCKS + PREP_CB, blk, 0, stream>>>(
            src, (const int4*)dst, w, bcnt, bedata,
            (const float4*)u, (const float4*)it, bxb4);
        k_spmm1b<<<SPMM_BLOCKS, blk, 0, stream>>>(bxb4, bcnt, bedata, bx1b4);
        k_spmm2b<<<SPMM_BLOCKS, blk, 0, stream>>>((const float4*)u, (const float4*)it,
                                                  bx1b4, bcnt, bedata, (float4*)out);
    } else if (ws_size >= need_csr) {
        hipMemsetAsync(cntp, 0, (size_t)NNODES * CPAD * sizeof(int), stream);
        k_prep <<<PREP_HB + PREP_CB, blk, 0, stream>>>((const int4*)dst, cntp,
                                              (const float4*)u, (const float4*)it, xb4);
        k_scan1<<<SCAN_NB, blk, 0, stream>>>(cntp, off, bscan);
        k_scan2<<<1, blk, 0, stream>>>(bscan);
        k_scan3<<<SCAN_NB, blk, 0, stream>>>(off, bscan, cntp);
        k_fill_win<<<FILL_BLOCKS, blk, 0, stream>>>(src, (const int4*)dst, w, cntp, edata);
        k_spmm1<<<SPMM_BLOCKS, blk, 0, stream>>>(xb4, off, edata, x1b4);
        k_spmm2<<<SPMM_BLOCKS, blk, 0, stream>>>((const float4*)u, (const float4*)it,
                                                 x1b4, off, edata, (float4*)out);
    } else {
        float* A = (float*)d_ws;
        hipMemsetAsync(out, 0, nd * sizeof(float), stream);
        long long nthreads = (long long)NEDGES * 16;
        int sblocks = (int)((nthreads + 255) / 256);
        scatter_l1<<<sblocks, blk, 0, stream>>>(u, it, out, src, dst, w);
        hipMemsetAsync(A, 0, nd * sizeof(float), stream);
        scatter_gen<<<sblocks, blk, 0, stream>>>(out, A, src, dst, w);
        final_kernel<<<(NNODES * EDIM / 4 + 255) / 256, blk, 0, stream>>>(
            (const float4*)u, (const float4*)it, (const float4*)A, (float4*)out);
    }
}

// Round 7
// 433.285 us; speedup vs baseline: 1.2263x; 1.0179x over previous
//
#include <hip/hip_runtime.h>
#include <hip/hip_bf16.h>

#define NUSERS 200000
#define NITEMS 100000
#define NNODES 300000
#define EDIM   64
#define NEDGES 2000000
#define FILLB  2048                      // hist/fill blocks (MUST match A<->B)
#define PREP_CB 2048                     // convert blocks (grid-stride)
#define NBKT   586                       // coarse buckets: dst>>9, 512 nodes each
#define SPMM_BLOCKS 2048                 // 8 blocks/CU persistent
#define SPMM_STRIDE (SPMM_BLOCKS * 4)    // one node per wave per sweep

typedef unsigned short u16;

__device__ __forceinline__ float bf2f(u16 h) {
    return __uint_as_float((unsigned)h << 16);
}
__device__ __forceinline__ u16 f2bf(float f) {
    union { __hip_bfloat16 b; u16 u; } c;
    c.b = __float2bfloat16(f);   // RNE
    return c.u;
}

// ============ ATOMIC-FREE CSR BUILD (LDS-only two-level counting sort) ============
// R6 post-mortem: 2M device-scope atomics cost ~110-130us regardless of layout
// (memory-side atomic unit, ~15-18G RMW/s). So: ZERO global atomics. Per-block
// LDS histograms over 586 coarse buckets -> scan the (bucket,block) matrix ->
// deterministic global slots -> per-bucket LDS sort to per-node CSR.

// Phase A: per-block LDS bucket histogram + fused bf16 convert
__global__ void k_prep3(const int4* __restrict__ dst4, int* __restrict__ bc,
                        const float4* __restrict__ uq, const float4* __restrict__ iq,
                        ushort4* __restrict__ xb4) {
    __shared__ int h[NBKT];
    int b = blockIdx.x;
    if (b < FILLB) {
        for (int k = threadIdx.x; k < NBKT; k += 256) h[k] = 0;
        __syncthreads();
        for (int i = b * 256 + threadIdx.x; i < NEDGES / 4; i += FILLB * 256) {
            int4 d = dst4[i];
            atomicAdd(&h[d.x >> 9], 1);     // LDS atomic (per-CU, fast)
            atomicAdd(&h[d.y >> 9], 1);
            atomicAdd(&h[d.z >> 9], 1);
            atomicAdd(&h[d.w >> 9], 1);
        }
        __syncthreads();
        for (int k = threadIdx.x; k < NBKT; k += 256)
            bc[k * FILLB + b] = h[k];       // [bucket][block] matrix
    } else {
        for (int i = (b - FILLB) * 256 + threadIdx.x; i < NNODES * 16;
             i += PREP_CB * 256) {
            float4 v = (i < NUSERS * 16) ? uq[i] : iq[i - NUSERS * 16];
            ushort4 hh;
            hh.x = f2bf(v.x); hh.y = f2bf(v.y); hh.z = f2bf(v.z); hh.w = f2bf(v.w);
            xb4[i] = hh;
        }
    }
}

// Phase B1: per-bucket exclusive scan over its 2048 block counts (in place)
__global__ void k_scanb(int* __restrict__ bc, int* __restrict__ btot) {
    __shared__ int s[256];
    int j = blockIdx.x;                 // bucket
    int t = threadIdx.x;
    int base = j * FILLB + t * 8;
    int v[8];
    int sum = 0;
#pragma unroll
    for (int m = 0; m < 8; ++m) { v[m] = bc[base + m]; sum += v[m]; }
    s[t] = sum;
    __syncthreads();
    for (int o = 1; o < 256; o <<= 1) {
        int x = (t >= o) ? s[t - o] : 0;
        __syncthreads();
        s[t] += x;
        __syncthreads();
    }
    int excl = s[t] - sum;
#pragma unroll
    for (int m = 0; m < 8; ++m) { int x = v[m]; bc[base + m] = excl; excl += x; }
    if (t == 255) btot[j] = s[255];
}

// Phase B2: exclusive scan of bucket totals -> bucket bases (+ off sentinel)
__global__ void k_scant(const int* __restrict__ btot, int* __restrict__ bbase,
                        int* __restrict__ off) {
    __shared__ int s[256];
    __shared__ int carry;
    int t = threadIdx.x;
    if (t == 0) carry = 0;
    __syncthreads();
    for (int base = 0; base < NBKT; base += 256) {
        int i = base + t;
        int v = (i < NBKT) ? btot[i] : 0;
        s[t] = v;
        __syncthreads();
        for (int o = 1; o < 256; o <<= 1) {
            int x = (t >= o) ? s[t - o] : 0;
            __syncthreads();
            s[t] += x;
            __syncthreads();
        }
        if (i < NBKT) bbase[i] = s[t] - v + carry;
        __syncthreads();
        if (t == 0) carry += s[255];
        __syncthreads();
    }
    if (t == 0) { bbase[NBKT] = carry; off[NNODES] = NEDGES; }
}

// Phase C: deterministic scatter into bucket-grouped staging (NO global atomics).
// Same grid + same traversal as k_prep3's hist half -> identical edge sets.
__global__ void k_fill3(const int4* __restrict__ dst4, const int4* __restrict__ src4,
                        const float4* __restrict__ w4, const int* __restrict__ bc,
                        const int* __restrict__ bbase,
                        int* __restrict__ dstv, int2* __restrict__ sw) {
    __shared__ int cur[NBKT];
    int b = blockIdx.x;
    for (int k = threadIdx.x; k < NBKT; k += 256)
        cur[k] = bbase[k] + bc[k * FILLB + b];
    __syncthreads();
    for (int i = b * 256 + threadIdx.x; i < NEDGES / 4; i += FILLB * 256) {
        int4 d = dst4[i];
        int4 sv = src4[i];
        float4 wv = w4[i];
        int p;
        p = atomicAdd(&cur[d.x >> 9], 1);   // LDS atomic
        dstv[p] = d.x; sw[p] = make_int2(sv.x, __float_as_int(wv.x));
        p = atomicAdd(&cur[d.y >> 9], 1);
        dstv[p] = d.y; sw[p] = make_int2(sv.y, __float_as_int(wv.y));
        p = atomicAdd(&cur[d.z >> 9], 1);
        dstv[p] = d.z; sw[p] = make_int2(sv.z, __float_as_int(wv.z));
        p = atomicAdd(&cur[d.w >> 9], 1);
        dstv[p] = d.w; sw[p] = make_int2(sv.w, __float_as_int(wv.w));
    }
}

// Phase D: per-bucket LDS sort to per-node CSR (one 512-thread block per bucket)
__global__ void k_build(const int* __restrict__ bbase, const int* __restrict__ dstv,
                        const int2* __restrict__ sw,
                        int* __restrict__ off, int2* __restrict__ edata) {
    __shared__ int cnt[512];
    __shared__ int s[512];
    __shared__ int cur[512];
    int j = blockIdx.x;
    int t = threadIdx.x;
    int lo = bbase[j], hi = bbase[j + 1];
    cnt[t] = 0;
    __syncthreads();
    for (int r = lo + t; r < hi; r += 512)
        atomicAdd(&cnt[dstv[r] & 511], 1);
    __syncthreads();
    int c = cnt[t];
    s[t] = c;
    __syncthreads();
    for (int o = 1; o < 512; o <<= 1) {
        int x = (t >= o) ? s[t - o] : 0;
        __syncthreads();
        s[t] += x;
        __syncthreads();
    }
    int excl = lo + s[t] - c;
    cur[t] = excl;
    int node = j * 512 + t;
    if (node < NNODES) off[node] = excl;
    __syncthreads();
    for (int r = lo + t; r < hi; r += 512) {
        int p = atomicAdd(&cur[dstv[r] & 511], 1);
        edata[p] = sw[r];
    }
}

// ---------------- gather SpMM (R1/R5-measured optimum; unchanged) ----------------

__device__ __forceinline__ float4 bfrow(const ushort4* __restrict__ xb4, int s, int l16) {
    const ushort4* p = (const ushort4*)((const char*)xb4 +
                       (((unsigned)s << 7) + ((unsigned)l16 << 3)));
    ushort4 h = *p;
    float4 v;
    v.x = bf2f(h.x); v.y = bf2f(h.y); v.z = bf2f(h.z); v.w = bf2f(h.w);
    return v;
}

__device__ __forceinline__ int2 ld_edge(const int2* __restrict__ e, unsigned i) {
    return *(const int2*)((const char*)e + (i << 3));
}

__global__ __launch_bounds__(256, 8)
void k_spmm1(const ushort4* __restrict__ xb4, const int* __restrict__ off,
             const int2* __restrict__ edata, ushort4* __restrict__ x1b4) {
    const int wid  = threadIdx.x >> 6;
    const int lane = threadIdx.x & 63;
    const int q    = lane >> 4;          // edge slot 0..3
    const int l16  = lane & 15;          // 16 lanes x ushort4 = 64 dims
    int n = blockIdx.x * 4 + wid;
    int o0 = off[n];
    int o1 = off[n + 1];
    while (n < NNODES) {
        int nn = n + SPMM_STRIDE;
        int no0 = 0, no1 = 0;
        if (nn < NNODES) { no0 = off[nn]; no1 = off[nn + 1]; }  // prefetch
        int deg = o1 - o0;
        int cap = o1 - 1; if (cap < 0) cap = 0;
        int b0 = o0 + q;
        int p0 = b0;      if (p0 > cap) p0 = cap;
        int p1 = b0 + 4;  if (p1 > cap) p1 = cap;
        int p2 = b0 + 8;  if (p2 > cap) p2 = cap;
        int p3 = b0 + 12; if (p3 > cap) p3 = cap;
        int2 e0 = ld_edge(edata, p0);
        int2 e1 = ld_edge(edata, p1);
        int2 e2 = ld_edge(edata, p2);
        int2 e3 = ld_edge(edata, p3);
        float4 v0 = make_float4(0.f, 0.f, 0.f, 0.f);
        float4 v1 = v0, v2 = v0, v3 = v0;
        if (q < deg)      v0 = bfrow(xb4, e0.x, l16);
        if (q + 4 < deg)  v1 = bfrow(xb4, e1.x, l16);
        if (q + 8 < deg)  v2 = bfrow(xb4, e2.x, l16);
        if (q + 12 < deg) v3 = bfrow(xb4, e3.x, l16);
        float w0 = __int_as_float(e0.y), w1 = __int_as_float(e1.y);
        float w2 = __int_as_float(e2.y), w3 = __int_as_float(e3.y);
        float4 a0, a1;
        a0.x = w0 * v0.x; a0.y = w0 * v0.y; a0.z = w0 * v0.z; a0.w = w0 * v0.w;
        a1.x = w1 * v1.x; a1.y = w1 * v1.y; a1.z = w1 * v1.z; a1.w = w1 * v1.w;
        a0.x += w2 * v2.x; a0.y += w2 * v2.y; a0.z += w2 * v2.z; a0.w += w2 * v2.w;
        a1.x += w3 * v3.x; a1.y += w3 * v3.y; a1.z += w3 * v3.z; a1.w += w3 * v3.w;
        if (deg > 16) {                       // rare tail
            for (int p = b0 + 16; p < o1; p += 4) {
                int2 e = ld_edge(edata, p);
                float4 v = bfrow(xb4, e.x, l16);
                float w = __int_as_float(e.y);
                a0.x += w * v.x; a0.y += w * v.y; a0.z += w * v.z; a0.w += w * v.w;
            }
        }
        a0.x += a1.x; a0.y += a1.y; a0.z += a1.z; a0.w += a1.w;
        a0.x += __shfl_xor(a0.x, 16, 64); a0.y += __shfl_xor(a0.y, 16, 64);
        a0.z += __shfl_xor(a0.z, 16, 64); a0.w += __shfl_xor(a0.w, 16, 64);
        a0.x += __shfl_xor(a0.x, 32, 64); a0.y += __shfl_xor(a0.y, 32, 64);
        a0.z += __shfl_xor(a0.z, 32, 64); a0.w += __shfl_xor(a0.w, 32, 64);
        if (q == 0) {
            ushort4 h;
            h.x = f2bf(a0.x); h.y = f2bf(a0.y); h.z = f2bf(a0.z); h.w = f2bf(a0.w);
            x1b4[(size_t)n * 16 + l16] = h;
        }
        n = nn; o0 = no0; o1 = no1;
    }
}

__global__ __launch_bounds__(256, 8)
void k_spmm2(const float4* __restrict__ uq, const float4* __restrict__ iq,
             const ushort4* __restrict__ x1b4, const int* __restrict__ off,
             const int2* __restrict__ edata, float4* __restrict__ outq) {
    const int wid  = threadIdx.x >> 6;
    const int lane = threadIdx.x & 63;
    const int q    = lane >> 4;
    const int l16  = lane & 15;
    int n = blockIdx.x * 4 + wid;
    int o0 = off[n];
    int o1 = off[n + 1];
    while (n < NNODES) {
        int nn = n + SPMM_STRIDE;
        int no0 = 0, no1 = 0;
        if (nn < NNODES) { no0 = off[nn]; no1 = off[nn + 1]; }
        int deg = o1 - o0;
        int cap = o1 - 1; if (cap < 0) cap = 0;
        int b0 = o0 + q;
        int p0 = b0;      if (p0 > cap) p0 = cap;
        int p1 = b0 + 4;  if (p1 > cap) p1 = cap;
        int p2 = b0 + 8;  if (p2 > cap) p2 = cap;
        int p3 = b0 + 12; if (p3 > cap) p3 = cap;
        int2 e0 = ld_edge(edata, p0);
        int2 e1 = ld_edge(edata, p1);
        int2 e2 = ld_edge(edata, p2);
        int2 e3 = ld_edge(edata, p3);
        float4 v0 = make_float4(0.f, 0.f, 0.f, 0.f);
        float4 v1 = v0, v2 = v0, v3 = v0;
        if (q < deg)      v0 = bfrow(x1b4, e0.x, l16);
        if (q + 4 < deg)  v1 = bfrow(x1b4, e1.x, l16);
        if (q + 8 < deg)  v2 = bfrow(x1b4, e2.x, l16);
        if (q + 12 < deg) v3 = bfrow(x1b4, e3.x, l16);
        float w0 = __int_as_float(e0.y), w1 = __int_as_float(e1.y);
        float w2 = __int_as_float(e2.y), w3 = __int_as_float(e3.y);
        float4 a0, a1;
        a0.x = w0 * v0.x; a0.y = w0 * v0.y; a0.z = w0 * v0.z; a0.w = w0 * v0.w;
        a1.x = w1 * v1.x; a1.y = w1 * v1.y; a1.z = w1 * v1.z; a1.w = w1 * v1.w;
        a0.x += w2 * v2.x; a0.y += w2 * v2.y; a0.z += w2 * v2.z; a0.w += w2 * v2.w;
        a1.x += w3 * v3.x; a1.y += w3 * v3.y; a1.z += w3 * v3.z; a1.w += w3 * v3.w;
        if (deg > 16) {
            for (int p = b0 + 16; p < o1; p += 4) {
                int2 e = ld_edge(edata, p);
                float4 v = bfrow(x1b4, e.x, l16);
                float w = __int_as_float(e.y);
                a0.x += w * v.x; a0.y += w * v.y; a0.z += w * v.z; a0.w += w * v.w;
            }
        }
        a0.x += a1.x; a0.y += a1.y; a0.z += a1.z; a0.w += a1.w;
        a0.x += __shfl_xor(a0.x, 16, 64); a0.y += __shfl_xor(a0.y, 16, 64);
        a0.z += __shfl_xor(a0.z, 16, 64); a0.w += __shfl_xor(a0.w, 16, 64);
        a0.x += __shfl_xor(a0.x, 32, 64); a0.y += __shfl_xor(a0.y, 32, 64);
        a0.z += __shfl_xor(a0.z, 32, 64); a0.w += __shfl_xor(a0.w, 32, 64);
        if (q == 0) {
            size_t ridx = (size_t)n * 16 + l16;
            float4 x0 = (n < NUSERS) ? uq[ridx] : iq[ridx - (size_t)NUSERS * 16];
            float4 x1v = bfrow(x1b4, n, l16);
            const float s = 1.0f / 3.0f;
            float4 r;
            r.x = (x0.x + x1v.x + a0.x) * s;
            r.y = (x0.y + x1v.y + a0.y) * s;
            r.z = (x0.z + x1v.z + a0.z) * s;
            r.w = (x0.w + x1v.w + a0.w) * s;
            outq[ridx] = r;
        }
        n = nn; o0 = no0; o1 = no1;
    }
}

// ---------------- fallback (atomic path, if ws too small) ----------------

__global__ void scatter_l1(const float* __restrict__ u, const float* __restrict__ it,
                           float* __restrict__ y,
                           const int* __restrict__ src, const int* __restrict__ dst,
                           const float* __restrict__ w) {
    long long t = (long long)blockIdx.x * blockDim.x + threadIdx.x;
    int e = (int)(t >> 4);
    if (e >= NEDGES) return;
    int q = (int)(t & 15);
    int s = src[e], d = dst[e];
    float we = w[e];
    const float* xrow = (s < NUSERS) ? (u + (size_t)s * EDIM)
                                     : (it + (size_t)(s - NUSERS) * EDIM);
    float4 v = ((const float4*)xrow)[q];
    float* yp = y + (size_t)d * EDIM + q * 4;
    atomicAdd(yp + 0, we * v.x);
    atomicAdd(yp + 1, we * v.y);
    atomicAdd(yp + 2, we * v.z);
    atomicAdd(yp + 3, we * v.w);
}

__global__ void scatter_gen(const float* __restrict__ x, float* __restrict__ y,
                            const int* __restrict__ src, const int* __restrict__ dst,
                            const float* __restrict__ w) {
    long long t = (long long)blockIdx.x * blockDim.x + threadIdx.x;
    int e = (int)(t >> 4);
    if (e >= NEDGES) return;
    int q = (int)(t & 15);
    int s = src[e], d = dst[e];
    float we = w[e];
    float4 v = ((const float4*)(x + (size_t)s * EDIM))[q];
    float* yp = y + (size_t)d * EDIM + q * 4;
    atomicAdd(yp + 0, we * v.x);
    atomicAdd(yp + 1, we * v.y);
    atomicAdd(yp + 2, we * v.z);
    atomicAdd(yp + 3, we * v.w);
}

__global__ void final_kernel(const float4* __restrict__ u, const float4* __restrict__ it,
                             const float4* __restrict__ x2, float4* __restrict__ outq) {
    int i = blockIdx.x * blockDim.x + threadIdx.x;
    const int uq = NUSERS * EDIM / 4;
    const int nq = NNODES * EDIM / 4;
    if (i >= nq) return;
    float4 x0 = (i < uq) ? u[i] : it[i - uq];
    float4 x1 = outq[i];
    float4 a  = x2[i];
    const float s = 1.0f / 3.0f;
    float4 r;
    r.x = (x0.x + x1.x + a.x) * s;
    r.y = (x0.y + x1.y + a.y) * s;
    r.z = (x0.z + x1.z + a.z) * s;
    r.w = (x0.w + x1.w + a.w) * s;
    outq[i] = r;
}

// ---------------- launch ----------------

extern "C" void kernel_launch(void* const* d_in, const int* in_sizes, int n_in,
                              void* d_out, int out_size, void* d_ws, size_t ws_size,
                              hipStream_t stream) {
    const float* u   = (const float*)d_in[0];
    const float* it  = (const float*)d_in[1];
    const int*   src = (const int*)d_in[2];
    const int*   dst = (const int*)d_in[3];
    const float* w   = (const float*)d_in[4];
    float* out = (float*)d_out;

    const size_t nd = (size_t)NNODES * EDIM;
    dim3 blk(256);

    // ---- sort-path layout (~123 MB), all regions fully written before read ----
    int*     off   = (int*)d_ws;                        // NNODES+8
    int*     btot  = off + NNODES + 8;                  // 640 (>= NBKT)
    int*     bbase = btot + 640;                        // 640 (>= NBKT+1)
    int*     bc    = bbase + 640;                       // NBKT*FILLB (4.8 MB)
    int*     dstv  = bc + NBKT * FILLB;                 // NEDGES (8 MB)
    int2*    sw    = (int2*)(dstv + NEDGES);            // NEDGES (16 MB)
    int2*    edata = sw + NEDGES;                       // NEDGES (16 MB)
    ushort4* xb4   = (ushort4*)(edata + NEDGES);        // NNODES*16 (38.4 MB)
    ushort4* x1b4  = xb4 + (size_t)NNODES * 16;         // NNODES*16 (38.4 MB)
    const size_t need_sort =
        (size_t)(NNODES + 8 + 640 + 640 + NBKT * FILLB) * sizeof(int) +
        (size_t)NEDGES * sizeof(int) +
        (size_t)NEDGES * sizeof(int2) * 2 +
        (size_t)NNODES * 16 * sizeof(ushort4) * 2;

    if (ws_size >= need_sort) {
        // A: LDS bucket hist + convert (no memset needed anywhere)
        k_prep3<<<FILLB + PREP_CB, blk, 0, stream>>>(
            (const int4*)dst, bc, (const float4*)u, (const float4*)it, xb4);
        // B: scan (bucket,block) matrix + bucket bases
        k_scanb<<<NBKT, blk, 0, stream>>>(bc, btot);
        k_scant<<<1, blk, 0, stream>>>(btot, bbase, off);
        // C: deterministic bucket-grouped scatter (zero global atomics)
        k_fill3<<<FILLB, blk, 0, stream>>>(
            (const int4*)dst, (const int4*)src, (const float4*)w, bc, bbase, dstv, sw);
        // D: per-bucket LDS sort -> off[] + edata[]
        k_build<<<NBKT, dim3(512), 0, stream>>>(bbase, dstv, sw, off, edata);
        // SpMM x2 (measured optimum, unchanged)
        k_spmm1<<<SPMM_BLOCKS, blk, 0, stream>>>(xb4, off, edata, x1b4);
        k_spmm2<<<SPMM_BLOCKS, blk, 0, stream>>>((const float4*)u, (const float4*)it,
                                                 x1b4, off, edata, (float4*)out);
    } else {
        float* A = (float*)d_ws;
        hipMemsetAsync(out, 0, nd * sizeof(float), stream);
        long long nthreads = (long long)NEDGES * 16;
        int sblocks = (int)((nthreads + 255) / 256);
        scatter_l1<<<sblocks, blk, 0, stream>>>(u, it, out, src, dst, w);
        hipMemsetAsync(A, 0, nd * sizeof(float), stream);
        scatter_gen<<<sblocks, blk, 0, stream>>>(out, A, src, dst, w);
        final_kernel<<<(NNODES * EDIM / 4 + 255) / 256, blk, 0, stream>>>(
            (const float4*)u, (const float4*)it, (const float4*)A, (float4*)out);
    }
}